// Round 1
// baseline (76.531 us; speedup 1.0000x reference)
//
#include <hip/hip_runtime.h>
#include <math.h>

constexpr int BDIM   = 1024;
constexpr int INDIM  = 512;
constexpr int OUTDIM = 512;

constexpr int TB  = 32;   // batch tile
constexpr int TO  = 64;   // out tile
constexpr int BK  = 16;   // k chunk
constexpr int TBP = 34;   // padded x-tile row stride (kills 4-way write conflict)
constexpr int TOP = 64;   // W1/W2 tile row stride
constexpr int TSP = 68;   // |W2^T| tile row stride (padded, keeps 16B row alignment)

__global__ void prep_k(const float* __restrict__ wh1, const float* __restrict__ mh1,
                       const float* __restrict__ wh2, const float* __restrict__ mh2,
                       float* __restrict__ W1, float* __restrict__ W2) {
    int e = blockIdx.x * 256 + threadIdx.x;
    if (e >= INDIM * OUTDIM) return;
    W1[e] = tanhf(wh1[e]) * (1.0f / (1.0f + expf(-mh1[e])));
    W2[e] = tanhf(wh2[e]) * (1.0f / (1.0f + expf(-mh2[e])));
}

__global__ __launch_bounds__(256) void main_k(
    const float* __restrict__ X, const float* __restrict__ W1,
    const float* __restrict__ W2, const float* __restrict__ G1,
    float* __restrict__ out)
{
    __shared__ __align__(16) float xs_x[BK][TBP];
    __shared__ __align__(16) float xs_l[BK][TBP];
    __shared__ __align__(16) float xs_s[BK][TBP];
    __shared__ __align__(16) float w1s[BK][TOP];
    __shared__ __align__(16) float w2s[BK][TOP];
    __shared__ __align__(16) float sws[BK][TSP];

    const int t  = threadIdx.x;
    const int o0 = blockIdx.x * TO;
    const int b0 = blockIdx.y * TB;
    const int tb = t >> 4;    // 0..15 -> 2 batch rows each
    const int to = t & 15;    // 0..15 -> 4 outputs each

    float a1[2][4] = {};
    float lm[2][4] = {};
    float pr[2][4] = {{1.f,1.f,1.f,1.f},{1.f,1.f,1.f,1.f}};

    for (int k0 = 0; k0 < INDIM; k0 += BK) {
        // ---- stage x tile (transposed): 32 rows x 16 k, threads 0..127
        if (t < 128) {
            int bl = t >> 2;
            int kc = (t & 3) * 4;
            const float4 v = *reinterpret_cast<const float4*>(&X[(b0 + bl) * INDIM + k0 + kc]);
            float xv[4] = {v.x, v.y, v.z, v.w};
            #pragma unroll
            for (int j = 0; j < 4; ++j) {
                float x = xv[j];
                xs_x[kc + j][bl] = x;
                xs_l[kc + j][bl] = logf(fmaxf(fabsf(x), 1e-7f));
                xs_s[kc + j][bl] = (x > 0.f) ? 0.f : ((x < 0.f) ? -2.f : -1.f);
            }
        }
        // ---- stage W1/W2 rows: 16 k x 64 o, one float4 per thread
        {
            int kk = t >> 4;
            int c4 = (t & 15) * 4;
            *reinterpret_cast<float4*>(&w1s[kk][c4]) =
                *reinterpret_cast<const float4*>(&W1[(k0 + kk) * OUTDIM + o0 + c4]);
            *reinterpret_cast<float4*>(&w2s[kk][c4]) =
                *reinterpret_cast<const float4*>(&W2[(k0 + kk) * OUTDIM + o0 + c4]);
        }
        // ---- stage |W2^T| tile (transposed): rows o0..o0+63, cols k0..k0+15
        {
            int orow = t >> 2;
            int kc   = (t & 3) * 4;
            const float4 v = *reinterpret_cast<const float4*>(&W2[(o0 + orow) * OUTDIM + k0 + kc]);
            float wv[4] = {v.x, v.y, v.z, v.w};
            #pragma unroll
            for (int j = 0; j < 4; ++j)
                sws[kc + j][orow] = fabsf(wv[j]);
        }
        __syncthreads();

        #pragma unroll
        for (int kk = 0; kk < BK; ++kk) {
            float2 xv = *reinterpret_cast<const float2*>(&xs_x[kk][tb * 2]);
            float2 lv = *reinterpret_cast<const float2*>(&xs_l[kk][tb * 2]);
            float2 sv = *reinterpret_cast<const float2*>(&xs_s[kk][tb * 2]);
            float4 w1v = *reinterpret_cast<const float4*>(&w1s[kk][to * 4]);
            float4 w2v = *reinterpret_cast<const float4*>(&w2s[kk][to * 4]);
            float4 swv = *reinterpret_cast<const float4*>(&sws[kk][to * 4]);
            float xa[2] = {xv.x, xv.y}, la[2] = {lv.x, lv.y}, sa[2] = {sv.x, sv.y};
            float w1a[4] = {w1v.x, w1v.y, w1v.z, w1v.w};
            float w2a[4] = {w2v.x, w2v.y, w2v.z, w2v.w};
            float swa[4] = {swv.x, swv.y, swv.z, swv.w};
            #pragma unroll
            for (int bb = 0; bb < 2; ++bb) {
                #pragma unroll
                for (int oo = 0; oo < 4; ++oo) {
                    a1[bb][oo] = fmaf(xa[bb], w1a[oo], a1[bb][oo]);
                    lm[bb][oo] = fmaf(la[bb], w2a[oo], lm[bb][oo]);
                    float tt   = fmaf(sa[bb], swa[oo], 1.0f);
                    pr[bb][oo] *= tt;
                }
            }
        }
        __syncthreads();
    }

    // ---- epilogue
    float g[4];
    #pragma unroll
    for (int oo = 0; oo < 4; ++oo)
        g[oo] = 1.0f / (1.0f + expf(-G1[o0 + to * 4 + oo]));

    #pragma unroll
    for (int bb = 0; bb < 2; ++bb) {
        float4 r;
        float* rp = &r.x;
        #pragma unroll
        for (int oo = 0; oo < 4; ++oo) {
            float m1 = expf(fminf(lm[bb][oo], 20.0f));
            float s  = fminf(fmaxf(pr[bb][oo], -1.0f), 1.0f);
            rp[oo] = g[oo] * a1[bb][oo] + (1.0f - g[oo]) * m1 * s;
        }
        *reinterpret_cast<float4*>(&out[(b0 + tb * 2 + bb) * OUTDIM + o0 + to * 4]) = r;
    }
}

extern "C" void kernel_launch(void* const* d_in, const int* in_sizes, int n_in,
                              void* d_out, int out_size, void* d_ws, size_t ws_size,
                              hipStream_t stream) {
    const float* X   = (const float*)d_in[0];
    const float* wh1 = (const float*)d_in[1];
    const float* mh1 = (const float*)d_in[2];
    const float* wh2 = (const float*)d_in[3];
    const float* mh2 = (const float*)d_in[4];
    const float* G1  = (const float*)d_in[5];
    float* out = (float*)d_out;
    float* W1  = (float*)d_ws;
    float* W2  = W1 + INDIM * OUTDIM;

    prep_k<<<dim3((INDIM * OUTDIM + 255) / 256), 256, 0, stream>>>(wh1, mh1, wh2, mh2, W1, W2);
    main_k<<<dim3(OUTDIM / TO, BDIM / TB), 256, 0, stream>>>(X, W1, W2, G1, out);
}

// Round 2
// 49.528 us; speedup vs baseline: 1.5452x; 1.5452x over previous
//
#include <hip/hip_runtime.h>
#include <math.h>

constexpr int BDIM   = 1024;
constexpr int INDIM  = 512;
constexpr int OUTDIM = 512;

constexpr int TB = 32;    // batch tile
constexpr int TO = 64;    // out tile
constexpr int BK = 16;    // k chunk per stage
constexpr int NG = 4;     // in-block k-split groups
constexpr int KCH = INDIM / NG;   // 128 per group

// per-group staging layout (in floats)
constexpr int XS_SZ = BK * 34;            // x tiles, padded stride 34
constexpr int WS_SZ = BK * 64;            // W1/W2 row tiles
constexpr int SW_SZ = BK * 68;            // |W2^T| tile, padded stride 68
constexpr int GSTG  = 3 * XS_SZ + 2 * WS_SZ + SW_SZ;   // 4768 floats
constexpr int NOUT  = TB * TO;            // 2048 outputs per block
constexpr int GPART = 3 * NOUT;           // 6144 floats of partials per group
constexpr int SMEM_FLOATS = NG * GPART;   // 24576 floats = 96 KiB (> NG*GSTG)

__global__ void prep_k(const float* __restrict__ wh1, const float* __restrict__ mh1,
                       const float* __restrict__ wh2, const float* __restrict__ mh2,
                       float* __restrict__ W1, float* __restrict__ W2) {
    int e = blockIdx.x * 256 + threadIdx.x;
    if (e >= INDIM * OUTDIM) return;
    W1[e] = tanhf(wh1[e]) * (1.0f / (1.0f + expf(-mh1[e])));
    W2[e] = tanhf(wh2[e]) * (1.0f / (1.0f + expf(-mh2[e])));
}

__global__ __launch_bounds__(1024) void main_k(
    const float* __restrict__ X, const float* __restrict__ W1,
    const float* __restrict__ W2, const float* __restrict__ G1,
    float* __restrict__ out)
{
    __shared__ __align__(16) float smem[SMEM_FLOATS];

    const int t  = threadIdx.x;
    const int g  = t >> 8;        // k-split group 0..3
    const int lt = t & 255;       // lane within group
    const int o0 = blockIdx.x * TO;
    const int b0 = blockIdx.y * TB;
    const int tb = lt >> 4;       // 0..15 -> 2 batch rows each
    const int to = lt & 15;       // 0..15 -> 4 outputs each

    float* stg  = smem + g * GSTG;
    float* xs_x = stg;
    float* xs_l = stg + XS_SZ;
    float* xs_s = stg + 2 * XS_SZ;
    float* w1s  = stg + 3 * XS_SZ;
    float* w2s  = stg + 3 * XS_SZ + WS_SZ;
    float* sws  = stg + 3 * XS_SZ + 2 * WS_SZ;

    float a1[2][4] = {};
    float lm[2][4] = {};
    float pr[2][4] = {{1.f,1.f,1.f,1.f},{1.f,1.f,1.f,1.f}};

    const int kbeg = g * KCH;
    for (int k0 = kbeg; k0 < kbeg + KCH; k0 += BK) {
        // ---- stage x tile (transposed): 32 rows x 16 k, group threads 0..127
        if (lt < 128) {
            int bl = lt >> 2;
            int kc = (lt & 3) * 4;
            const float4 v = *reinterpret_cast<const float4*>(&X[(b0 + bl) * INDIM + k0 + kc]);
            float xv[4] = {v.x, v.y, v.z, v.w};
            #pragma unroll
            for (int j = 0; j < 4; ++j) {
                float x = xv[j];
                xs_x[(kc + j) * 34 + bl] = x;
                xs_l[(kc + j) * 34 + bl] = logf(fmaxf(fabsf(x), 1e-7f));
                xs_s[(kc + j) * 34 + bl] = (x > 0.f) ? 0.f : ((x < 0.f) ? -2.f : -1.f);
            }
        }
        // ---- stage W1/W2 rows: 16 k x 64 o, one float4 per thread
        {
            int kk = lt >> 4;
            int c4 = (lt & 15) * 4;
            *reinterpret_cast<float4*>(&w1s[kk * 64 + c4]) =
                *reinterpret_cast<const float4*>(&W1[(k0 + kk) * OUTDIM + o0 + c4]);
            *reinterpret_cast<float4*>(&w2s[kk * 64 + c4]) =
                *reinterpret_cast<const float4*>(&W2[(k0 + kk) * OUTDIM + o0 + c4]);
        }
        // ---- stage |W2^T| tile (transposed): rows o0..o0+63, cols k0..k0+15
        {
            int orow = lt >> 2;
            int kc   = (lt & 3) * 4;
            const float4 v = *reinterpret_cast<const float4*>(&W2[(o0 + orow) * OUTDIM + k0 + kc]);
            sws[(kc + 0) * 68 + orow] = fabsf(v.x);
            sws[(kc + 1) * 68 + orow] = fabsf(v.y);
            sws[(kc + 2) * 68 + orow] = fabsf(v.z);
            sws[(kc + 3) * 68 + orow] = fabsf(v.w);
        }
        __syncthreads();

        #pragma unroll
        for (int kk = 0; kk < BK; ++kk) {
            float2 xv = *reinterpret_cast<const float2*>(&xs_x[kk * 34 + tb * 2]);
            float2 lv = *reinterpret_cast<const float2*>(&xs_l[kk * 34 + tb * 2]);
            float2 sv = *reinterpret_cast<const float2*>(&xs_s[kk * 34 + tb * 2]);
            float4 w1v = *reinterpret_cast<const float4*>(&w1s[kk * 64 + to * 4]);
            float4 w2v = *reinterpret_cast<const float4*>(&w2s[kk * 64 + to * 4]);
            float4 swv = *reinterpret_cast<const float4*>(&sws[kk * 68 + to * 4]);
            float xa[2] = {xv.x, xv.y}, la[2] = {lv.x, lv.y}, sa[2] = {sv.x, sv.y};
            float w1a[4] = {w1v.x, w1v.y, w1v.z, w1v.w};
            float w2a[4] = {w2v.x, w2v.y, w2v.z, w2v.w};
            float swa[4] = {swv.x, swv.y, swv.z, swv.w};
            #pragma unroll
            for (int bb = 0; bb < 2; ++bb) {
                #pragma unroll
                for (int oo = 0; oo < 4; ++oo) {
                    a1[bb][oo] = fmaf(xa[bb], w1a[oo], a1[bb][oo]);
                    lm[bb][oo] = fmaf(la[bb], w2a[oo], lm[bb][oo]);
                    float tt   = fmaf(sa[bb], swa[oo], 1.0f);
                    pr[bb][oo] *= tt;
                }
            }
        }
        __syncthreads();
    }

    // ---- dump per-group partials (staging region is dead after last barrier)
    {
        float* part = smem + g * GPART;
        #pragma unroll
        for (int bb = 0; bb < 2; ++bb) {
            int r = tb * 2 + bb;
            #pragma unroll
            for (int oo = 0; oo < 4; ++oo) {
                int idx = r * 64 + to * 4 + oo;
                part[0 * NOUT + idx] = a1[bb][oo];
                part[1 * NOUT + idx] = lm[bb][oo];
                part[2 * NOUT + idx] = pr[bb][oo];
            }
        }
    }
    __syncthreads();

    // ---- combine across groups + epilogue: 1024 threads x 2 outputs
    {
        int idx2 = t * 2;
        int r = idx2 >> 6, c = idx2 & 63;
        float A0 = 0.f, A1 = 0.f, L0 = 0.f, L1 = 0.f, P0 = 1.f, P1 = 1.f;
        #pragma unroll
        for (int gg = 0; gg < NG; ++gg) {
            const float* pp = smem + gg * GPART;
            float2 a = *reinterpret_cast<const float2*>(&pp[0 * NOUT + r * 64 + c]);
            float2 l = *reinterpret_cast<const float2*>(&pp[1 * NOUT + r * 64 + c]);
            float2 p = *reinterpret_cast<const float2*>(&pp[2 * NOUT + r * 64 + c]);
            A0 += a.x; A1 += a.y;
            L0 += l.x; L1 += l.y;
            P0 *= p.x; P1 *= p.y;
        }
        float g0 = 1.0f / (1.0f + expf(-G1[o0 + c]));
        float g1v = 1.0f / (1.0f + expf(-G1[o0 + c + 1]));
        float m0 = expf(fminf(L0, 20.0f));
        float m1 = expf(fminf(L1, 20.0f));
        float s0 = fminf(fmaxf(P0, -1.0f), 1.0f);
        float s1 = fminf(fmaxf(P1, -1.0f), 1.0f);
        float2 res;
        res.x = g0 * A0 + (1.0f - g0) * m0 * s0;
        res.y = g1v * A1 + (1.0f - g1v) * m1 * s1;
        *reinterpret_cast<float2*>(&out[(b0 + r) * OUTDIM + o0 + c]) = res;
    }
}

extern "C" void kernel_launch(void* const* d_in, const int* in_sizes, int n_in,
                              void* d_out, int out_size, void* d_ws, size_t ws_size,
                              hipStream_t stream) {
    const float* X   = (const float*)d_in[0];
    const float* wh1 = (const float*)d_in[1];
    const float* mh1 = (const float*)d_in[2];
    const float* wh2 = (const float*)d_in[3];
    const float* mh2 = (const float*)d_in[4];
    const float* G1  = (const float*)d_in[5];
    float* out = (float*)d_out;
    float* W1  = (float*)d_ws;
    float* W2  = W1 + INDIM * OUTDIM;

    prep_k<<<dim3((INDIM * OUTDIM + 255) / 256), 256, 0, stream>>>(wh1, mh1, wh2, mh2, W1, W2);
    main_k<<<dim3(OUTDIM / TO, BDIM / TB), 1024, 0, stream>>>(X, W1, W2, G1, out);
}